// Round 1
// 172.470 us; speedup vs baseline: 1.0887x; 1.0887x over previous
//
#include <hip/hip_runtime.h>
#include <hip/hip_bf16.h>
#include <math.h>

#define EMBED  512
#define HEADS  2
#define HDIM   256
#define NTEXT  64
#define NWORD  32
#define NVID   128
#define NFRM   64

typedef __attribute__((ext_vector_type(8))) short      short8;    // 8 bf16 = A/B frag
typedef __attribute__((ext_vector_type(8))) unsigned short ushort8;
typedef __attribute__((ext_vector_type(4))) float      float4v;   // C/D frag
typedef __attribute__((ext_vector_type(4))) unsigned short ushort4v;

__device__ __forceinline__ unsigned short f2bf(float x) {
    __hip_bfloat16 h = __float2bfloat16(x);
    return *(unsigned short*)&h;
}
__device__ __forceinline__ float bf2f(unsigned short u) {
    __hip_bfloat16 h = *(__hip_bfloat16*)&u;
    return __bfloat162float(h);
}

// async global->LDS, 16B per lane. LDS dest is linear (base + lane*16) in all
// uses below, which is exactly the HW requirement.
__device__ __forceinline__ void gload_lds16(unsigned short* dst, const unsigned short* src) {
#if __has_builtin(__builtin_amdgcn_global_load_lds)
    __builtin_amdgcn_global_load_lds((const __attribute__((address_space(1))) void*)src,
                                     (__attribute__((address_space(3))) void*)dst,
                                     16, 0, 0);
#else
    *(ushort8*)dst = *(const ushort8*)src;
#endif
}

// ===========================================================================
// cvt5: one-shot fp32 -> bf16 of text, video, Wq, Wk, Wv (same RNE rounding
// proj_qkv used to do per-tile, so GEMM inputs are bit-identical).
// dst region = partg area of ws (dead until attn9 runs).
// Layout (ushort offsets): text@0 (1048576), video@1048576 (4194304),
// wq@5242880, wk@5505024, wv@5767168 (262144 each). Total 11.5 MB < 16 MB.
// ===========================================================================
__global__ __launch_bounds__(256)
void cvt5(const float* __restrict__ s0, const float* __restrict__ s1,
          const float* __restrict__ s2, const float* __restrict__ s3,
          const float* __restrict__ s4, unsigned short* __restrict__ dst) {
    const int y = blockIdx.y;
    const float* s; size_t off; int n4;
    if (y == 0)      { s = s0; off = 0;       n4 = 262144;  }
    else if (y == 1) { s = s1; off = 1048576; n4 = 1048576; }
    else if (y == 2) { s = s2; off = 5242880; n4 = 65536;   }
    else if (y == 3) { s = s3; off = 5505024; n4 = 65536;   }
    else             { s = s4; off = 5767168; n4 = 65536;   }
    unsigned short* d = dst + off;
    for (int i = blockIdx.x * 256 + threadIdx.x; i < n4; i += 512 * 256) {
        float4v f = ((const float4v*)s)[i];
        ((ushort4v*)d)[i] = (ushort4v){f2bf(f.x), f2bf(f.y), f2bf(f.z), f2bf(f.w)};
    }
}

// ===========================================================================
// proj_qkv v3: same GEMM/epilogues as v2 (verified), but A and W are now
// pre-converted bf16 -> staging is a pure ushort8 copy (half the global
// traffic, zero cvt VALU in the k-loop).
//   mb <  32 : q  = (text @ Wq^T + bq)/16 -> bf16 row-major [2048][512]
//   mb < 160 : K  -> frag-major Kgf[h][a][ft4][kq8][l64][j8]
//   else     : V  -> frag-major Vgf[h][a][nt16][kqv2][l64][j8]
// ===========================================================================
__global__ __launch_bounds__(256)
void proj_qkv(const unsigned short* __restrict__ text, const unsigned short* __restrict__ video,
              const unsigned short* __restrict__ Wqb, const float* __restrict__ bq,
              const unsigned short* __restrict__ Wkb, const float* __restrict__ bk,
              const unsigned short* __restrict__ Wvb, const float* __restrict__ bv,
              unsigned short* __restrict__ qout,
              unsigned short* __restrict__ Kgf, unsigned short* __restrict__ Vgf) {
    const int mb = blockIdx.x, nb = blockIdx.y;
    const int bj = nb * 64;
    const unsigned short *A, *W;
    const float* bias;
    int op, arow, a = 0;
    if (mb < 32)       { op = 0; A = text;  W = Wqb; bias = bq; arow = mb * 64; }
    else if (mb < 160) { op = 1; A = video; W = Wkb; bias = bk; a = mb - 32;  arow = a * 64; }
    else               { op = 2; A = video; W = Wvb; bias = bv; a = mb - 160; arow = a * 64; }

    __shared__ __align__(16) unsigned char smem[64 * 72 * 2 * 2];
    unsigned short (*Ab)[72] = (unsigned short (*)[72])smem;
    unsigned short (*Wb)[72] = (unsigned short (*)[72])(smem + 64 * 72 * 2);
    unsigned short (*Eb)[72] = (unsigned short (*)[72])smem;

    const int tid = threadIdx.x;
    const int w = tid >> 6, lane = tid & 63;
    const int lm = lane & 15, qd = lane >> 4;

    float4v acc[4];
    #pragma unroll
    for (int nt = 0; nt < 4; ++nt) acc[nt] = (float4v){0.f, 0.f, 0.f, 0.f};

    for (int k0 = 0; k0 < 512; k0 += 64) {
        #pragma unroll
        for (int it = 0; it < 2; ++it) {
            const int s = tid + it * 256;          // 512 ushort8 slots
            const int r = s >> 3, c8 = (s & 7) * 8;
            *(ushort8*)&Ab[r][c8] = *(const ushort8*)&A[(size_t)(arow + r) * 512 + k0 + c8];
            *(ushort8*)&Wb[r][c8] = *(const ushort8*)&W[(size_t)(bj + r) * 512 + k0 + c8];
        }
        __syncthreads();
        #pragma unroll
        for (int kq = 0; kq < 2; ++kq) {
            const short8 af = *(const short8*)&Ab[w * 16 + lm][kq * 32 + qd * 8];
            #pragma unroll
            for (int nt = 0; nt < 4; ++nt) {
                const short8 bf = *(const short8*)&Wb[nt * 16 + lm][kq * 32 + qd * 8];
                acc[nt] = __builtin_amdgcn_mfma_f32_16x16x32_bf16(af, bf, acc[nt], 0, 0, 0);
            }
        }
        __syncthreads();
    }

    if (op == 0) {
        #pragma unroll
        for (int nt = 0; nt < 4; ++nt) {
            const int c = bj + nt * 16 + lm;
            const float bb = bias[c];
            #pragma unroll
            for (int reg = 0; reg < 4; ++reg) {
                const int r = arow + w * 16 + qd * 4 + reg;
                qout[(size_t)r * 512 + c] = f2bf((acc[nt][reg] + bb) * 0.0625f);
            }
        }
        return;
    }

    const int h = bj >> 8;
    const int bj_rel = bj & 255;

    if (op == 1) {
        #pragma unroll
        for (int nt = 0; nt < 4; ++nt) {
            const int dl = nt * 16 + lm;
            const float bb = bias[bj + dl];
            #pragma unroll
            for (int reg = 0; reg < 4; ++reg)
                Eb[w * 16 + qd * 4 + reg][dl] = f2bf(acc[nt][reg] + bb);
        }
        __syncthreads();
        const size_t base = ((size_t)(h * 128 + a)) * 16384;
        #pragma unroll
        for (int i = 0; i < 2; ++i) {
            const int s = tid + i * 256;
            const int ntf = s >> 7, kqr = (s >> 6) & 1, l = s & 63;
            const int v = ntf * 16 + (l & 15);
            const int dl = kqr * 32 + (l >> 4) * 8;
            ushort8 val = *(const ushort8*)&Eb[v][dl];
            *(ushort8*)&Kgf[base + ((size_t)(ntf * 8 + (bj_rel >> 5) + kqr) * 64 + l) * 8] = val;
        }
    } else {
        #pragma unroll
        for (int nt = 0; nt < 4; ++nt) {
            const int dl = nt * 16 + lm;
            const float bb = bias[bj + dl];
            #pragma unroll
            for (int reg = 0; reg < 4; ++reg)
                Eb[dl][w * 16 + qd * 4 + reg] = f2bf(acc[nt][reg] + bb);
        }
        __syncthreads();
        const size_t base = ((size_t)(h * 128 + a)) * 16384;
        #pragma unroll
        for (int i = 0; i < 2; ++i) {
            const int s = tid + i * 256;
            const int ntr = s >> 7, kqv = (s >> 6) & 1, l = s & 63;
            const int dl = ntr * 16 + (l & 15);
            const int v0 = kqv * 32 + (l >> 4) * 8;
            ushort8 val = *(const ushort8*)&Eb[dl][v0];
            *(ushort8*)&Vgf[base + ((size_t)(((bj_rel >> 4) + ntr) * 2 + kqv) * 64 + l) * 8] = val;
        }
    }
}

// ===========================================================================
// attn9: grid (8 chunks, 2 h, 16 tg) = 256 blocks, 512 thr (8 waves), 1/CU.
// Wave w: text wt = w>>1 (FULL 32 words), role bit fh = w&1:
//   QK: frame-half fh (swapped operands mfma(K,Q) -> D[frame][word])
//   PV: d-half fh
// Halves per-MFMA LDS frag traffic vs attn8 (each K/V frag feeds 2 word
// tiles). Split softmax: per-wave (m,s) over 32 frames, combined across the
// wave pair via a tiny Ex exchange. P handed off through LDS (frag-major).
// K/V double-buffered, staged by global_load_lds 2 vids ahead; visibility
// rides on the __syncthreads vmcnt drains (data issued >=1 full iter early).
// ===========================================================================
__global__ __launch_bounds__(512, 2)
void attn9(const unsigned short* __restrict__ Kgf,
           const unsigned short* __restrict__ Vgf,
           const unsigned short* __restrict__ q,    // bf16, pre-scaled 1/16
           unsigned short* __restrict__ partg) {    // [8][2048][512] bf16
    const int c  = blockIdx.x;
    const int h  = blockIdx.y;
    const int tg = blockIdx.z;
    const int tid = threadIdx.x;
    const int w = tid >> 6, lane = tid & 63;
    const int lm = lane & 15, qd = lane >> 4;
    const int wt = w >> 1;       // text slot 0..3
    const int fh = w & 1;        // frame-half (QK) / d-half (PV)
    const int b = tg * 4 + wt;

    __shared__ __align__(16) unsigned short Kb[2][16384];     // 64 KB
    __shared__ __align__(16) unsigned short Vb[2][16384];     // 64 KB
    __shared__ __align__(16) unsigned short Pf[4][2][2][512]; // [text][mt][kqv][l*8+j] 16 KB
    __shared__ __align__(16) float Ex[4][2][2][16][2];        // [text][fh][mt][word16][m,s] 2 KB

    // Q B-frags for the wave's full text: 16 frags = 64 VGPRs
    short8 qf[2][8];
    #pragma unroll
    for (int mt = 0; mt < 2; ++mt)
        #pragma unroll
        for (int kq = 0; kq < 8; ++kq)
            qf[mt][kq] = *(const short8*)
                &q[((size_t)(b * 32 + mt * 16 + lm)) * 512 + h * 256 + kq * 32 + qd * 8];

    float4v pacc[2][8];
    #pragma unroll
    for (int mt = 0; mt < 2; ++mt)
        #pragma unroll
        for (int nd = 0; nd < 8; ++nd) pacc[mt][nd] = (float4v){0.f, 0.f, 0.f, 0.f};

    const size_t vb0 = (size_t)(h * 128 + c * 16) * 16384;

    // prologue: stage vids 0 and 1 into the two buffers
    #pragma unroll
    for (int i = 0; i < 4; ++i) {
        const int s = tid + i * 512;
        gload_lds16(&Kb[0][(size_t)s * 8], &Kgf[vb0 + (size_t)s * 8]);
        gload_lds16(&Vb[0][(size_t)s * 8], &Vgf[vb0 + (size_t)s * 8]);
    }
    #pragma unroll
    for (int i = 0; i < 4; ++i) {
        const int s = tid + i * 512;
        gload_lds16(&Kb[1][(size_t)s * 8], &Kgf[vb0 + 16384 + (size_t)s * 8]);
        gload_lds16(&Vb[1][(size_t)s * 8], &Vgf[vb0 + 16384 + (size_t)s * 8]);
    }
    __syncthreads();

    for (int ai = 0; ai < 16; ++ai) {
        const int cur = ai & 1;

        // ---- QK: D[frame][word], frames = fh*32 + nt*16 + qd*4 + reg ----
        float4v lacc[2][2];   // [nt frame-tile][mt word-tile]
        #pragma unroll
        for (int nt = 0; nt < 2; ++nt)
            #pragma unroll
            for (int mt = 0; mt < 2; ++mt) lacc[nt][mt] = (float4v){0.f, 0.f, 0.f, 0.f};
        #pragma unroll
        for (int kq = 0; kq < 8; ++kq) {
            #pragma unroll
            for (int nt = 0; nt < 2; ++nt) {
                const short8 kf = *(const short8*)
                    &Kb[cur][(((fh * 2 + nt) * 8 + kq) * 64 + lane) * 8];
                lacc[nt][0] = __builtin_amdgcn_mfma_f32_16x16x32_bf16(kf, qf[0][kq], lacc[nt][0], 0, 0, 0);
                lacc[nt][1] = __builtin_amdgcn_mfma_f32_16x16x32_bf16(kf, qf[1][kq], lacc[nt][1], 0, 0, 0);
            }
        }

        // ---- local softmax over this wave's 32 frames (8 in-lane + 2 shfl) ----
        float m2[2], sv[2], e[2][2][4];
        #pragma unroll
        for (int mt = 0; mt < 2; ++mt) {
            float mm = lacc[0][mt][0];
            #pragma unroll
            for (int nt = 0; nt < 2; ++nt)
                #pragma unroll
                for (int r = 0; r < 4; ++r) mm = fmaxf(mm, lacc[nt][mt][r]);
            mm = fmaxf(mm, __shfl_xor(mm, 16));
            mm = fmaxf(mm, __shfl_xor(mm, 32));
            float ss = 0.f;
            #pragma unroll
            for (int nt = 0; nt < 2; ++nt)
                #pragma unroll
                for (int r = 0; r < 4; ++r) {
                    const float ev = __expf(lacc[nt][mt][r] - mm);
                    e[mt][nt][r] = ev;
                    ss += ev;
                }
            ss += __shfl_xor(ss, 16);
            ss += __shfl_xor(ss, 32);
            m2[mt] = mm; sv[mt] = ss;
            if (qd == 0) {
                Ex[wt][fh][mt][lm][0] = mm;
                Ex[wt][fh][mt][lm][1] = ss;
            }
        }
        __syncthreads();   // B3: (m,s) exchange visible

        // ---- combine halves, scale P, write frag-major P ----
        #pragma unroll
        for (int mt = 0; mt < 2; ++mt) {
            const float om = Ex[wt][fh ^ 1][mt][lm][0];
            const float os = Ex[wt][fh ^ 1][mt][lm][1];
            const float M   = fmaxf(m2[mt], om);
            const float den = sv[mt] * __expf(m2[mt] - M) + os * __expf(om - M);
            const float fac = __expf(m2[mt] - M) / den;
            #pragma unroll
            for (int nt = 0; nt < 2; ++nt) {
                ushort4v pv;
                pv.x = f2bf(e[mt][nt][0] * fac);
                pv.y = f2bf(e[mt][nt][1] * fac);
                pv.z = f2bf(e[mt][nt][2] * fac);
                pv.w = f2bf(e[mt][nt][3] * fac);
                // fl = nt*16 + qd*4 + reg; dest (l', j) = (lm + 16*(fl>>3), fl&7)
                *(ushort4v*)&Pf[wt][mt][fh][(lm + 16 * (nt * 2 + (qd >> 1))) * 8 + (qd & 1) * 4] = pv;
            }
        }
        __syncthreads();   // B4: P visible to the partner wave

        // ---- PV: out[word][d], d = fh*128 + nd*16 + lm ----
        #pragma unroll
        for (int kqv = 0; kqv < 2; ++kqv) {
            const short8 pf0 = *(const short8*)&Pf[wt][0][kqv][lane * 8];
            const short8 pf1 = *(const short8*)&Pf[wt][1][kqv][lane * 8];
            #pragma unroll
            for (int nd = 0; nd < 8; ++nd) {
                const short8 vf = *(const short8*)
                    &Vb[cur][(((fh * 8 + nd) * 2 + kqv) * 64 + lane) * 8];
                pacc[0][nd] = __builtin_amdgcn_mfma_f32_16x16x32_bf16(pf0, vf, pacc[0][nd], 0, 0, 0);
                pacc[1][nd] = __builtin_amdgcn_mfma_f32_16x16x32_bf16(pf1, vf, pacc[1][nd], 0, 0, 0);
            }
        }
        __syncthreads();   // B1: all waves done with Kb/Vb[cur] and Pf

        // stage vid ai+2 into the buffer just freed (2-ahead prefetch)
        if (ai < 14) {
            const size_t kb = vb0 + (size_t)(ai + 2) * 16384;
            #pragma unroll
            for (int i = 0; i < 4; ++i) {
                const int s = tid + i * 512;
                gload_lds16(&Kb[cur][(size_t)s * 8], &Kgf[kb + (size_t)s * 8]);
                gload_lds16(&Vb[cur][(size_t)s * 8], &Vgf[kb + (size_t)s * 8]);
            }
        }
    }

    // epilogue: row = b*32 + h*16 + (t>>1), col = (t&1)*256 + d (verified remap)
    unsigned short* part = partg + (size_t)c * 1048576;
    #pragma unroll
    for (int mt = 0; mt < 2; ++mt)
        #pragma unroll
        for (int nd = 0; nd < 8; ++nd)
            #pragma unroll
            for (int r = 0; r < 4; ++r) {
                const int t = mt * 16 + qd * 4 + r;
                const int d = fh * 128 + nd * 16 + lm;
                const int row = b * 32 + h * 16 + (t >> 1);
                const int col = (t & 1) * 256 + d;
                part[(size_t)row * 512 + col] = f2bf(pacc[mt][nd][r]);
            }
}

// ===========================================================================
// reduce8: partg[0][i] = (sum_p partg[p][i]) / 128, bf16 (single rounding).
// ===========================================================================
__global__ __launch_bounds__(256)
void reduce8(unsigned short* __restrict__ partg) {
    const size_t i = ((size_t)blockIdx.x * 256 + threadIdx.x) * 8;
    float s[8];
    #pragma unroll
    for (int j = 0; j < 8; ++j) s[j] = 0.f;
    #pragma unroll
    for (int p = 0; p < 8; ++p) {
        ushort8 u = *(const ushort8*)&partg[(size_t)p * 1048576 + i];
        #pragma unroll
        for (int j = 0; j < 8; ++j) s[j] += bf2f(u[j]);
    }
    ushort8 o;
    #pragma unroll
    for (int j = 0; j < 8; ++j) o[j] = f2bf(s[j] * 0.0078125f);
    *(ushort8*)&partg[i] = o;
}

// ===========================================================================
// proj_o: out = Abf @ Wo^T + bo, fp32 out. (unchanged, verified)
// ===========================================================================
__global__ __launch_bounds__(256)
void proj_o(const unsigned short* __restrict__ Abf, const float* __restrict__ W,
            const float* __restrict__ bias, float* __restrict__ C) {
    __shared__ __align__(16) unsigned short Ab[64][72];
    __shared__ __align__(16) unsigned short Wb[64][72];
    const int tid = threadIdx.x;
    const int bi = blockIdx.x * 64, bj = blockIdx.y * 64;
    const int w = tid >> 6, lane = tid & 63;
    const int lm = lane & 15, qd = lane >> 4;

    float4v acc[4];
    #pragma unroll
    for (int nt = 0; nt < 4; ++nt) acc[nt] = (float4v){0.f, 0.f, 0.f, 0.f};

    for (int k0 = 0; k0 < 512; k0 += 64) {
        #pragma unroll
        for (int it = 0; it < 2; ++it) {
            const int s = tid + it * 256;
            const int r = s >> 3, c8 = (s & 7) * 8;
            *(ushort8*)&Ab[r][c8] = *(const ushort8*)&Abf[(size_t)(bi + r) * 512 + k0 + c8];
        }
        #pragma unroll
        for (int it = 0; it < 4; ++it) {
            const int s = tid + it * 256;
            const int r = s >> 4, c4 = (s & 15) * 4;
            float4v fw = *(const float4v*)&W[(size_t)(bj + r) * 512 + k0 + c4];
            *(ushort4v*)&Wb[r][c4] = (ushort4v){f2bf(fw.x), f2bf(fw.y), f2bf(fw.z), f2bf(fw.w)};
        }
        __syncthreads();
        #pragma unroll
        for (int kq = 0; kq < 2; ++kq) {
            const short8 af = *(const short8*)&Ab[w * 16 + lm][kq * 32 + qd * 8];
            #pragma unroll
            for (int nt = 0; nt < 4; ++nt) {
                const short8 bf = *(const short8*)&Wb[nt * 16 + lm][kq * 32 + qd * 8];
                acc[nt] = __builtin_amdgcn_mfma_f32_16x16x32_bf16(af, bf, acc[nt], 0, 0, 0);
            }
        }
        __syncthreads();
    }
    #pragma unroll
    for (int nt = 0; nt < 4; ++nt) {
        const int cc = bj + nt * 16 + lm;
        const float bb = bias[cc];
        #pragma unroll
        for (int reg = 0; reg < 4; ++reg) {
            const int r = bi + w * 16 + qd * 4 + reg;
            C[(size_t)r * 512 + cc] = acc[nt][reg] + bb;
        }
    }
}

extern "C" void kernel_launch(void* const* d_in, const int* in_sizes, int n_in,
                              void* d_out, int out_size, void* d_ws, size_t ws_size,
                              hipStream_t stream) {
    const float* text  = (const float*)d_in[0];
    const float* video = (const float*)d_in[1];
    const float* Wq = (const float*)d_in[2];
    const float* bq = (const float*)d_in[3];
    const float* Wk = (const float*)d_in[4];
    const float* bk = (const float*)d_in[5];
    const float* Wv = (const float*)d_in[6];
    const float* bv = (const float*)d_in[7];
    const float* Wo = (const float*)d_in[8];
    const float* bo = (const float*)d_in[9];

    // ws (32 MB): Kgf 8 MB @0; Vgf 8 MB @8MB; partg bf16 [8][2048][512] @16MB.
    // The partg region doubles as the bf16-input scratch (11.5 MB) for cvt5 +
    // proj_qkv — it is only overwritten by attn9, which runs after proj_qkv.
    // q bf16 [2048][512] (pre-scaled 1/16) lives in d_out [0,2MB) until proj_o.
    unsigned short* Kgf   = (unsigned short*)d_ws;
    unsigned short* Vgf   = (unsigned short*)((char*)d_ws + (8u << 20));
    unsigned short* partg = (unsigned short*)((char*)d_ws + (16u << 20));
    unsigned short* textbf  = partg;
    unsigned short* videobf = partg + 1048576;
    unsigned short* wqbf    = partg + 5242880;
    unsigned short* wkbf    = partg + 5505024;
    unsigned short* wvbf    = partg + 5767168;
    unsigned short* qbf   = (unsigned short*)d_out;
    float*          out   = (float*)d_out;

    cvt5<<<dim3(512, 5), 256, 0, stream>>>(text, video, Wq, Wk, Wv, partg);
    proj_qkv<<<dim3(288, 8), 256, 0, stream>>>(textbf, videobf, wqbf, bq, wkbf, bk,
                                               wvbf, bv, qbf, Kgf, Vgf);
    attn9<<<dim3(8, 2, 16), 512, 0, stream>>>(Kgf, Vgf, qbf, partg);
    reduce8<<<dim3(512), 256, 0, stream>>>(partg);
    proj_o<<<dim3(32, 8), 256, 0, stream>>>(partg, Wo, bo, out);
}

// Round 2
// 169.401 us; speedup vs baseline: 1.1084x; 1.0181x over previous
//
#include <hip/hip_runtime.h>
#include <hip/hip_bf16.h>
#include <math.h>

#define EMBED  512
#define HEADS  2
#define HDIM   256
#define NTEXT  64
#define NWORD  32
#define NVID   128
#define NFRM   64

typedef __attribute__((ext_vector_type(8))) short      short8;    // 8 bf16 = A/B frag
typedef __attribute__((ext_vector_type(8))) unsigned short ushort8;
typedef __attribute__((ext_vector_type(4))) float      float4v;   // C/D frag
typedef __attribute__((ext_vector_type(4))) unsigned short ushort4v;

__device__ __forceinline__ unsigned short f2bf(float x) {
    __hip_bfloat16 h = __float2bfloat16(x);
    return *(unsigned short*)&h;
}
__device__ __forceinline__ float bf2f(unsigned short u) {
    __hip_bfloat16 h = *(__hip_bfloat16*)&u;
    return __bfloat162float(h);
}

// async global->LDS, 16B per lane. LDS dest must be wave-uniform base + lane*16
// (linear); all uses below satisfy that.
__device__ __forceinline__ void gload_lds16(unsigned short* dst, const unsigned short* src) {
#if __has_builtin(__builtin_amdgcn_global_load_lds)
    __builtin_amdgcn_global_load_lds((const __attribute__((address_space(1))) void*)src,
                                     (__attribute__((address_space(3))) void*)dst,
                                     16, 0, 0);
#else
    *(ushort8*)dst = *(const ushort8*)src;
#endif
}

// ===========================================================================
// cvt5: one-shot fp32 -> bf16 of text, video, Wq, Wk, Wv (same RNE rounding
// as before — GEMM inputs bit-identical). dst = partg region (dead until attn).
// Layout (ushort offsets): text@0 (1048576), video@1048576 (4194304),
// wq@5242880, wk@5505024, wv@5767168 (262144 each).
// ===========================================================================
__global__ __launch_bounds__(256)
void cvt5(const float* __restrict__ s0, const float* __restrict__ s1,
          const float* __restrict__ s2, const float* __restrict__ s3,
          const float* __restrict__ s4, unsigned short* __restrict__ dst) {
    const int y = blockIdx.y;
    const float* s; size_t off; int n4;
    if (y == 0)      { s = s0; off = 0;       n4 = 262144;  }
    else if (y == 1) { s = s1; off = 1048576; n4 = 1048576; }
    else if (y == 2) { s = s2; off = 5242880; n4 = 65536;   }
    else if (y == 3) { s = s3; off = 5505024; n4 = 65536;   }
    else             { s = s4; off = 5767168; n4 = 65536;   }
    unsigned short* d = dst + off;
    for (int i = blockIdx.x * 256 + threadIdx.x; i < n4; i += 512 * 256) {
        float4v f = ((const float4v*)s)[i];
        ((ushort4v*)d)[i] = (ushort4v){f2bf(f.x), f2bf(f.y), f2bf(f.z), f2bf(f.w)};
    }
}

// ===========================================================================
// proj_qkv v4: global_load_lds staging (no VGPR round-trip, no ds_write) with
// XOR-swizzled LDS (T2 both-sides pattern, m97/m201):
//   LDS slot (row r, 16B-col c8)  <-  A[r][(c8 ^ (r&7))*8 ...]   (pre-swz src)
//   frag read col = (kq*32 + qd*8) ^ ((lm&7)*8)                  (swz read)
// XOR involution => round-trip exact; banks spread 8-way => conflict-free.
// Same MFMA math and verified K/V/q epilogues as v3.
//   mb <  32 : q  = (text @ Wq^T + bq)/16 -> bf16 row-major [2048][512]
//   mb < 160 : K  -> frag-major Kgf[h][a][ft4][kq8][l64][j8]
//   else     : V  -> frag-major Vgf[h][a][nt16][kqv2][l64][j8]
// ===========================================================================
__global__ __launch_bounds__(256)
void proj_qkv(const unsigned short* __restrict__ text, const unsigned short* __restrict__ video,
              const unsigned short* __restrict__ Wqb, const float* __restrict__ bq,
              const unsigned short* __restrict__ Wkb, const float* __restrict__ bk,
              const unsigned short* __restrict__ Wvb, const float* __restrict__ bv,
              unsigned short* __restrict__ qout,
              unsigned short* __restrict__ Kgf, unsigned short* __restrict__ Vgf) {
    const int mb = blockIdx.x, nb = blockIdx.y;
    const int bj = nb * 64;
    const unsigned short *A, *W;
    const float* bias;
    int op, arow, a = 0;
    if (mb < 32)       { op = 0; A = text;  W = Wqb; bias = bq; arow = mb * 64; }
    else if (mb < 160) { op = 1; A = video; W = Wkb; bias = bk; a = mb - 32;  arow = a * 64; }
    else               { op = 2; A = video; W = Wvb; bias = bv; a = mb - 160; arow = a * 64; }

    // AbL[64][64] @0 (8KB), WbL[64][64] @8KB (8KB); Eb[64][72] (9216B) overlays
    // for the epilogue (runs after the final barrier, A/W dead).
    __shared__ __align__(16) unsigned char smem[16384];
    unsigned short* AbL = (unsigned short*)smem;
    unsigned short* WbL = (unsigned short*)(smem + 8192);
    unsigned short (*Eb)[72] = (unsigned short (*)[72])smem;

    const int tid = threadIdx.x;
    const int w = tid >> 6, lane = tid & 63;
    const int lm = lane & 15, qd = lane >> 4;

    float4v acc[4];
    #pragma unroll
    for (int nt = 0; nt < 4; ++nt) acc[nt] = (float4v){0.f, 0.f, 0.f, 0.f};

    for (int k0 = 0; k0 < 512; k0 += 64) {
        // issue staging: 512 slots each for A and W, 2 gload_lds x2 per thread
        #pragma unroll
        for (int it = 0; it < 2; ++it) {
            const int s = tid + it * 256;           // 0..511
            const int r = s >> 3, c8 = s & 7;
            const int sc = (c8 ^ (r & 7)) * 8;      // pre-swizzled source col
            gload_lds16(&AbL[(size_t)s * 8], &A[(size_t)(arow + r) * 512 + k0 + sc]);
            gload_lds16(&WbL[(size_t)s * 8], &W[(size_t)(bj   + r) * 512 + k0 + sc]);
        }
        __syncthreads();    // vmcnt drained -> staged tile visible
        #pragma unroll
        for (int kq = 0; kq < 2; ++kq) {
            const int scol = (kq * 32 + qd * 8) ^ ((lm & 7) * 8);  // swizzled read col
            const short8 af = *(const short8*)&AbL[(w * 16 + lm) * 64 + scol];
            #pragma unroll
            for (int nt = 0; nt < 4; ++nt) {
                const short8 bf = *(const short8*)&WbL[(nt * 16 + lm) * 64 + scol];
                acc[nt] = __builtin_amdgcn_mfma_f32_16x16x32_bf16(af, bf, acc[nt], 0, 0, 0);
            }
        }
        __syncthreads();    // all reads done; next iter may overwrite
    }

    if (op == 0) {
        #pragma unroll
        for (int nt = 0; nt < 4; ++nt) {
            const int c = bj + nt * 16 + lm;
            const float bb = bias[c];
            #pragma unroll
            for (int reg = 0; reg < 4; ++reg) {
                const int r = arow + w * 16 + qd * 4 + reg;
                qout[(size_t)r * 512 + c] = f2bf((acc[nt][reg] + bb) * 0.0625f);
            }
        }
        return;
    }

    const int h = bj >> 8;
    const int bj_rel = bj & 255;

    if (op == 1) {
        #pragma unroll
        for (int nt = 0; nt < 4; ++nt) {
            const int dl = nt * 16 + lm;
            const float bb = bias[bj + dl];
            #pragma unroll
            for (int reg = 0; reg < 4; ++reg)
                Eb[w * 16 + qd * 4 + reg][dl] = f2bf(acc[nt][reg] + bb);
        }
        __syncthreads();
        const size_t base = ((size_t)(h * 128 + a)) * 16384;
        #pragma unroll
        for (int i = 0; i < 2; ++i) {
            const int s = tid + i * 256;
            const int ntf = s >> 7, kqr = (s >> 6) & 1, l = s & 63;
            const int v = ntf * 16 + (l & 15);
            const int dl = kqr * 32 + (l >> 4) * 8;
            ushort8 val = *(const ushort8*)&Eb[v][dl];
            *(ushort8*)&Kgf[base + ((size_t)(ntf * 8 + (bj_rel >> 5) + kqr) * 64 + l) * 8] = val;
        }
    } else {
        #pragma unroll
        for (int nt = 0; nt < 4; ++nt) {
            const int dl = nt * 16 + lm;
            const float bb = bias[bj + dl];
            #pragma unroll
            for (int reg = 0; reg < 4; ++reg)
                Eb[dl][w * 16 + qd * 4 + reg] = f2bf(acc[nt][reg] + bb);
        }
        __syncthreads();
        const size_t base = ((size_t)(h * 128 + a)) * 16384;
        #pragma unroll
        for (int i = 0; i < 2; ++i) {
            const int s = tid + i * 256;
            const int ntr = s >> 7, kqv = (s >> 6) & 1, l = s & 63;
            const int dl = ntr * 16 + (l & 15);
            const int v0 = kqv * 32 + (l >> 4) * 8;
            ushort8 val = *(const ushort8*)&Eb[dl][v0];
            *(ushort8*)&Vgf[base + ((size_t)(((bj_rel >> 4) + ntr) * 2 + kqv) * 64 + l) * 8] = val;
        }
    }
}

// ===========================================================================
// attn10: attn9 (verified) + s_setprio(1) around both MFMA clusters (T5).
// Grid (8 chunks, 2 h, 16 tg) = 256 blocks, 512 thr (8 waves), 1/CU.
// Wave w: text wt = w>>1 (full 32 words), role bit fh = w&1:
//   QK: frame-half fh (swapped operands mfma(K,Q) -> D[frame][word])
//   PV: d-half fh
// Split softmax combined across the wave pair via Ex; P via LDS (frag-major).
// K/V double-buffered, global_load_lds staged 2 vids ahead.
// ===========================================================================
__global__ __launch_bounds__(512, 2)
void attn10(const unsigned short* __restrict__ Kgf,
            const unsigned short* __restrict__ Vgf,
            const unsigned short* __restrict__ q,    // bf16, pre-scaled 1/16
            unsigned short* __restrict__ partg) {    // [8][2048][512] bf16
    const int c  = blockIdx.x;
    const int h  = blockIdx.y;
    const int tg = blockIdx.z;
    const int tid = threadIdx.x;
    const int w = tid >> 6, lane = tid & 63;
    const int lm = lane & 15, qd = lane >> 4;
    const int wt = w >> 1;       // text slot 0..3
    const int fh = w & 1;        // frame-half (QK) / d-half (PV)
    const int b = tg * 4 + wt;

    __shared__ __align__(16) unsigned short Kb[2][16384];     // 64 KB
    __shared__ __align__(16) unsigned short Vb[2][16384];     // 64 KB
    __shared__ __align__(16) unsigned short Pf[4][2][2][512]; // [text][mt][kqv][l*8+j] 16 KB
    __shared__ __align__(16) float Ex[4][2][2][16][2];        // [text][fh][mt][word16][m,s] 2 KB

    // Q B-frags for the wave's full text: 16 frags = 64 VGPRs
    short8 qf[2][8];
    #pragma unroll
    for (int mt = 0; mt < 2; ++mt)
        #pragma unroll
        for (int kq = 0; kq < 8; ++kq)
            qf[mt][kq] = *(const short8*)
                &q[((size_t)(b * 32 + mt * 16 + lm)) * 512 + h * 256 + kq * 32 + qd * 8];

    float4v pacc[2][8];
    #pragma unroll
    for (int mt = 0; mt < 2; ++mt)
        #pragma unroll
        for (int nd = 0; nd < 8; ++nd) pacc[mt][nd] = (float4v){0.f, 0.f, 0.f, 0.f};

    const size_t vb0 = (size_t)(h * 128 + c * 16) * 16384;

    // prologue: stage vids 0 and 1 into the two buffers
    #pragma unroll
    for (int i = 0; i < 4; ++i) {
        const int s = tid + i * 512;
        gload_lds16(&Kb[0][(size_t)s * 8], &Kgf[vb0 + (size_t)s * 8]);
        gload_lds16(&Vb[0][(size_t)s * 8], &Vgf[vb0 + (size_t)s * 8]);
    }
    #pragma unroll
    for (int i = 0; i < 4; ++i) {
        const int s = tid + i * 512;
        gload_lds16(&Kb[1][(size_t)s * 8], &Kgf[vb0 + 16384 + (size_t)s * 8]);
        gload_lds16(&Vb[1][(size_t)s * 8], &Vgf[vb0 + 16384 + (size_t)s * 8]);
    }
    __syncthreads();

    for (int ai = 0; ai < 16; ++ai) {
        const int cur = ai & 1;

        // ---- QK: D[frame][word], frames = fh*32 + nt*16 + qd*4 + reg ----
        float4v lacc[2][2];   // [nt frame-tile][mt word-tile]
        #pragma unroll
        for (int nt = 0; nt < 2; ++nt)
            #pragma unroll
            for (int mt = 0; mt < 2; ++mt) lacc[nt][mt] = (float4v){0.f, 0.f, 0.f, 0.f};
        __builtin_amdgcn_s_setprio(1);
        #pragma unroll
        for (int kq = 0; kq < 8; ++kq) {
            #pragma unroll
            for (int nt = 0; nt < 2; ++nt) {
                const short8 kf = *(const short8*)
                    &Kb[cur][(((fh * 2 + nt) * 8 + kq) * 64 + lane) * 8];
                lacc[nt][0] = __builtin_amdgcn_mfma_f32_16x16x32_bf16(kf, qf[0][kq], lacc[nt][0], 0, 0, 0);
                lacc[nt][1] = __builtin_amdgcn_mfma_f32_16x16x32_bf16(kf, qf[1][kq], lacc[nt][1], 0, 0, 0);
            }
        }
        __builtin_amdgcn_s_setprio(0);

        // ---- local softmax over this wave's 32 frames (8 in-lane + 2 shfl) ----
        float m2[2], sv[2], e[2][2][4];
        #pragma unroll
        for (int mt = 0; mt < 2; ++mt) {
            float mm = lacc[0][mt][0];
            #pragma unroll
            for (int nt = 0; nt < 2; ++nt)
                #pragma unroll
                for (int r = 0; r < 4; ++r) mm = fmaxf(mm, lacc[nt][mt][r]);
            mm = fmaxf(mm, __shfl_xor(mm, 16));
            mm = fmaxf(mm, __shfl_xor(mm, 32));
            float ss = 0.f;
            #pragma unroll
            for (int nt = 0; nt < 2; ++nt)
                #pragma unroll
                for (int r = 0; r < 4; ++r) {
                    const float ev = __expf(lacc[nt][mt][r] - mm);
                    e[mt][nt][r] = ev;
                    ss += ev;
                }
            ss += __shfl_xor(ss, 16);
            ss += __shfl_xor(ss, 32);
            m2[mt] = mm; sv[mt] = ss;
            if (qd == 0) {
                Ex[wt][fh][mt][lm][0] = mm;
                Ex[wt][fh][mt][lm][1] = ss;
            }
        }
        __syncthreads();   // B3: (m,s) exchange visible

        // ---- combine halves, scale P, write frag-major P ----
        #pragma unroll
        for (int mt = 0; mt < 2; ++mt) {
            const float om = Ex[wt][fh ^ 1][mt][lm][0];
            const float os = Ex[wt][fh ^ 1][mt][lm][1];
            const float M   = fmaxf(m2[mt], om);
            const float den = sv[mt] * __expf(m2[mt] - M) + os * __expf(om - M);
            const float fac = __expf(m2[mt] - M) / den;
            #pragma unroll
            for (int nt = 0; nt < 2; ++nt) {
                ushort4v pv;
                pv.x = f2bf(e[mt][nt][0] * fac);
                pv.y = f2bf(e[mt][nt][1] * fac);
                pv.z = f2bf(e[mt][nt][2] * fac);
                pv.w = f2bf(e[mt][nt][3] * fac);
                // fl = nt*16 + qd*4 + reg; dest (l', j) = (lm + 16*(fl>>3), fl&7)
                *(ushort4v*)&Pf[wt][mt][fh][(lm + 16 * (nt * 2 + (qd >> 1))) * 8 + (qd & 1) * 4] = pv;
            }
        }
        __syncthreads();   // B4: P visible to the partner wave

        // ---- PV: out[word][d], d = fh*128 + nd*16 + lm ----
        __builtin_amdgcn_s_setprio(1);
        #pragma unroll
        for (int kqv = 0; kqv < 2; ++kqv) {
            const short8 pf0 = *(const short8*)&Pf[wt][0][kqv][lane * 8];
            const short8 pf1 = *(const short8*)&Pf[wt][1][kqv][lane * 8];
            #pragma unroll
            for (int nd = 0; nd < 8; ++nd) {
                const short8 vf = *(const short8*)
                    &Vb[cur][(((fh * 8 + nd) * 2 + kqv) * 64 + lane) * 8];
                pacc[0][nd] = __builtin_amdgcn_mfma_f32_16x16x32_bf16(pf0, vf, pacc[0][nd], 0, 0, 0);
                pacc[1][nd] = __builtin_amdgcn_mfma_f32_16x16x32_bf16(pf1, vf, pacc[1][nd], 0, 0, 0);
            }
        }
        __builtin_amdgcn_s_setprio(0);
        __syncthreads();   // B1: all waves done with Kb/Vb[cur] and Pf

        // stage vid ai+2 into the buffer just freed (2-ahead prefetch)
        if (ai < 14) {
            const size_t kb = vb0 + (size_t)(ai + 2) * 16384;
            #pragma unroll
            for (int i = 0; i < 4; ++i) {
                const int s = tid + i * 512;
                gload_lds16(&Kb[cur][(size_t)s * 8], &Kgf[kb + (size_t)s * 8]);
                gload_lds16(&Vb[cur][(size_t)s * 8], &Vgf[kb + (size_t)s * 8]);
            }
        }
    }

    // epilogue: row = b*32 + h*16 + (t>>1), col = (t&1)*256 + d (verified remap)
    unsigned short* part = partg + (size_t)c * 1048576;
    #pragma unroll
    for (int mt = 0; mt < 2; ++mt)
        #pragma unroll
        for (int nd = 0; nd < 8; ++nd)
            #pragma unroll
            for (int r = 0; r < 4; ++r) {
                const int t = mt * 16 + qd * 4 + r;
                const int d = fh * 128 + nd * 16 + lm;
                const int row = b * 32 + h * 16 + (t >> 1);
                const int col = (t & 1) * 256 + d;
                part[(size_t)row * 512 + col] = f2bf(pacc[mt][nd][r]);
            }
}

// ===========================================================================
// reduce8: partg[0][i] = (sum_p partg[p][i]) / 128, bf16 (single rounding).
// ===========================================================================
__global__ __launch_bounds__(256)
void reduce8(unsigned short* __restrict__ partg) {
    const size_t i = ((size_t)blockIdx.x * 256 + threadIdx.x) * 8;
    float s[8];
    #pragma unroll
    for (int j = 0; j < 8; ++j) s[j] = 0.f;
    #pragma unroll
    for (int p = 0; p < 8; ++p) {
        ushort8 u = *(const ushort8*)&partg[(size_t)p * 1048576 + i];
        #pragma unroll
        for (int j = 0; j < 8; ++j) s[j] += bf2f(u[j]);
    }
    ushort8 o;
    #pragma unroll
    for (int j = 0; j < 8; ++j) o[j] = f2bf(s[j] * 0.0078125f);
    *(ushort8*)&partg[i] = o;
}

// ===========================================================================
// proj_o: out = Abf @ Wo^T + bo, fp32 out. (unchanged, verified)
// ===========================================================================
__global__ __launch_bounds__(256)
void proj_o(const unsigned short* __restrict__ Abf, const float* __restrict__ W,
            const float* __restrict__ bias, float* __restrict__ C) {
    __shared__ __align__(16) unsigned short Ab[64][72];
    __shared__ __align__(16) unsigned short Wb[64][72];
    const int tid = threadIdx.x;
    const int bi = blockIdx.x * 64, bj = blockIdx.y * 64;
    const int w = tid >> 6, lane = tid & 63;
    const int lm = lane & 15, qd = lane >> 4;

    float4v acc[4];
    #pragma unroll
    for (int nt = 0; nt < 4; ++nt) acc[nt] = (float4v){0.f, 0.f, 0.f, 0.f};

    for (int k0 = 0; k0 < 512; k0 += 64) {
        #pragma unroll
        for (int it = 0; it < 2; ++it) {
            const int s = tid + it * 256;
            const int r = s >> 3, c8 = (s & 7) * 8;
            *(ushort8*)&Ab[r][c8] = *(const ushort8*)&Abf[(size_t)(bi + r) * 512 + k0 + c8];
        }
        #pragma unroll
        for (int it = 0; it < 4; ++it) {
            const int s = tid + it * 256;
            const int r = s >> 4, c4 = (s & 15) * 4;
            float4v fw = *(const float4v*)&W[(size_t)(bj + r) * 512 + k0 + c4];
            *(ushort4v*)&Wb[r][c4] = (ushort4v){f2bf(fw.x), f2bf(fw.y), f2bf(fw.z), f2bf(fw.w)};
        }
        __syncthreads();
        #pragma unroll
        for (int kq = 0; kq < 2; ++kq) {
            const short8 af = *(const short8*)&Ab[w * 16 + lm][kq * 32 + qd * 8];
            #pragma unroll
            for (int nt = 0; nt < 4; ++nt) {
                const short8 bf = *(const short8*)&Wb[nt * 16 + lm][kq * 32 + qd * 8];
                acc[nt] = __builtin_amdgcn_mfma_f32_16x16x32_bf16(af, bf, acc[nt], 0, 0, 0);
            }
        }
        __syncthreads();
    }
    #pragma unroll
    for (int nt = 0; nt < 4; ++nt) {
        const int cc = bj + nt * 16 + lm;
        const float bb = bias[cc];
        #pragma unroll
        for (int reg = 0; reg < 4; ++reg) {
            const int r = bi + w * 16 + qd * 4 + reg;
            C[(size_t)r * 512 + cc] = acc[nt][reg] + bb;
        }
    }
}

extern "C" void kernel_launch(void* const* d_in, const int* in_sizes, int n_in,
                              void* d_out, int out_size, void* d_ws, size_t ws_size,
                              hipStream_t stream) {
    const float* text  = (const float*)d_in[0];
    const float* video = (const float*)d_in[1];
    const float* Wq = (const float*)d_in[2];
    const float* bq = (const float*)d_in[3];
    const float* Wk = (const float*)d_in[4];
    const float* bk = (const float*)d_in[5];
    const float* Wv = (const float*)d_in[6];
    const float* bv = (const float*)d_in[7];
    const float* Wo = (const float*)d_in[8];
    const float* bo = (const float*)d_in[9];

    // ws (32 MB): Kgf 8 MB @0; Vgf 8 MB @8MB; partg bf16 [8][2048][512] @16MB.
    // The partg region doubles as the bf16-input scratch (11.5 MB) for cvt5 +
    // proj_qkv — it is only overwritten by attn10, which runs after proj_qkv.
    // q bf16 [2048][512] (pre-scaled 1/16) lives in d_out [0,2MB) until proj_o.
    unsigned short* Kgf   = (unsigned short*)d_ws;
    unsigned short* Vgf   = (unsigned short*)((char*)d_ws + (8u << 20));
    unsigned short* partg = (unsigned short*)((char*)d_ws + (16u << 20));
    unsigned short* textbf  = partg;
    unsigned short* videobf = partg + 1048576;
    unsigned short* wqbf    = partg + 5242880;
    unsigned short* wkbf    = partg + 5505024;
    unsigned short* wvbf    = partg + 5767168;
    unsigned short* qbf   = (unsigned short*)d_out;
    float*          out   = (float*)d_out;

    cvt5<<<dim3(512, 5), 256, 0, stream>>>(text, video, Wq, Wk, Wv, partg);
    proj_qkv<<<dim3(288, 8), 256, 0, stream>>>(textbf, videobf, wqbf, bq, wkbf, bk,
                                               wvbf, bv, qbf, Kgf, Vgf);
    attn10<<<dim3(8, 2, 16), 512, 0, stream>>>(Kgf, Vgf, qbf, partg);
    reduce8<<<dim3(512), 256, 0, stream>>>(partg);
    proj_o<<<dim3(32, 8), 256, 0, stream>>>(partg, Wo, bo, out);
}

// Round 3
// 166.622 us; speedup vs baseline: 1.1269x; 1.0167x over previous
//
#include <hip/hip_runtime.h>
#include <hip/hip_bf16.h>
#include <math.h>

#define EMBED  512
#define HEADS  2
#define HDIM   256
#define NTEXT  64
#define NWORD  32
#define NVID   128
#define NFRM   64

typedef __attribute__((ext_vector_type(8))) short      short8;    // 8 bf16 = A/B frag
typedef __attribute__((ext_vector_type(8))) unsigned short ushort8;
typedef __attribute__((ext_vector_type(4))) float      float4v;   // C/D frag
typedef __attribute__((ext_vector_type(4))) unsigned short ushort4v;

__device__ __forceinline__ unsigned short f2bf(float x) {
    __hip_bfloat16 h = __float2bfloat16(x);
    return *(unsigned short*)&h;
}
__device__ __forceinline__ float bf2f(unsigned short u) {
    __hip_bfloat16 h = *(__hip_bfloat16*)&u;
    return __bfloat162float(h);
}

// async global->LDS, 16B per lane. LDS dest must be wave-uniform base + lane*16
// (linear); all uses below satisfy that.
__device__ __forceinline__ void gload_lds16(unsigned short* dst, const unsigned short* src) {
#if __has_builtin(__builtin_amdgcn_global_load_lds)
    __builtin_amdgcn_global_load_lds((const __attribute__((address_space(1))) void*)src,
                                     (__attribute__((address_space(3))) void*)dst,
                                     16, 0, 0);
#else
    *(ushort8*)dst = *(const ushort8*)src;
#endif
}

// ===========================================================================
// cvt5: one-shot fp32 -> bf16 of text, video, Wq, Wk, Wv (same RNE rounding
// as before — GEMM inputs bit-identical). dst = partg region (dead until attn).
// Layout (ushort offsets): text@0 (1048576), video@1048576 (4194304),
// wq@5242880, wk@5505024, wv@5767168 (262144 each).
// ===========================================================================
__global__ __launch_bounds__(256)
void cvt5(const float* __restrict__ s0, const float* __restrict__ s1,
          const float* __restrict__ s2, const float* __restrict__ s3,
          const float* __restrict__ s4, unsigned short* __restrict__ dst) {
    const int y = blockIdx.y;
    const float* s; size_t off; int n4;
    if (y == 0)      { s = s0; off = 0;       n4 = 262144;  }
    else if (y == 1) { s = s1; off = 1048576; n4 = 1048576; }
    else if (y == 2) { s = s2; off = 5242880; n4 = 65536;   }
    else if (y == 3) { s = s3; off = 5505024; n4 = 65536;   }
    else             { s = s4; off = 5767168; n4 = 65536;   }
    unsigned short* d = dst + off;
    for (int i = blockIdx.x * 256 + threadIdx.x; i < n4; i += 512 * 256) {
        float4v f = ((const float4v*)s)[i];
        ((ushort4v*)d)[i] = (ushort4v){f2bf(f.x), f2bf(f.y), f2bf(f.z), f2bf(f.w)};
    }
}

// ===========================================================================
// proj_qkv v5: T3-minimum 2-phase pipeline. Double-buffered LDS (2 x 16 KB);
// per k-step: issue STAGE(next tile) FIRST, then ds_read+MFMA on current,
// then ONE barrier (drains the just-issued loads under compute cover).
// Barrier count per block: 16 -> 9. Same XOR-swizzle (T2 both-sides) and
// identical verified epilogues/remaps as v4.
//   mb <  32 : q  = (text @ Wq^T + bq)/16 -> bf16 row-major [2048][512]
//   mb < 160 : K  -> frag-major Kgf[h][a][ft4][kq8][l64][j8]
//   else     : V  -> frag-major Vgf[h][a][nt16][kqv2][l64][j8]
// ===========================================================================
__global__ __launch_bounds__(256)
void proj_qkv(const unsigned short* __restrict__ text, const unsigned short* __restrict__ video,
              const unsigned short* __restrict__ Wqb, const float* __restrict__ bq,
              const unsigned short* __restrict__ Wkb, const float* __restrict__ bk,
              const unsigned short* __restrict__ Wvb, const float* __restrict__ bv,
              unsigned short* __restrict__ qout,
              unsigned short* __restrict__ Kgf, unsigned short* __restrict__ Vgf) {
    const int mb = blockIdx.x, nb = blockIdx.y;
    const int bj = nb * 64;
    const unsigned short *A, *W;
    const float* bias;
    int op, arow, a = 0;
    if (mb < 32)       { op = 0; A = text;  W = Wqb; bias = bq; arow = mb * 64; }
    else if (mb < 160) { op = 1; A = video; W = Wkb; bias = bk; a = mb - 32;  arow = a * 64; }
    else               { op = 2; A = video; W = Wvb; bias = bv; a = mb - 160; arow = a * 64; }

    // double-buffered: AbL[buf] @ buf*16384, WbL[buf] @ buf*16384+8192 (32 KB)
    // Eb[64][72] (9216 B) overlays buf0 for the epilogue (after final barrier).
    __shared__ __align__(16) unsigned char smem[32768];
    unsigned short (*Eb)[72] = (unsigned short (*)[72])smem;

    const int tid = threadIdx.x;
    const int w = tid >> 6, lane = tid & 63;
    const int lm = lane & 15, qd = lane >> 4;

    float4v acc[4];
    #pragma unroll
    for (int nt = 0; nt < 4; ++nt) acc[nt] = (float4v){0.f, 0.f, 0.f, 0.f};

    // staging: 512 slots each for A and W; slot s=(r,c8) sources the
    // pre-swizzled column (c8 ^ (r&7)) so the LDS image is XOR-swizzled.
    auto STAGE = [&](int buf, int k0) {
        unsigned short* AbL = (unsigned short*)(smem + buf * 16384);
        unsigned short* WbL = (unsigned short*)(smem + buf * 16384 + 8192);
        #pragma unroll
        for (int it = 0; it < 2; ++it) {
            const int s = tid + it * 256;           // 0..511
            const int r = s >> 3, c8 = s & 7;
            const int sc = (c8 ^ (r & 7)) * 8;      // pre-swizzled source col
            gload_lds16(&AbL[(size_t)s * 8], &A[(size_t)(arow + r) * 512 + k0 + sc]);
            gload_lds16(&WbL[(size_t)s * 8], &W[(size_t)(bj   + r) * 512 + k0 + sc]);
        }
    };

    STAGE(0, 0);
    __syncthreads();                 // drain prologue loads
    int cur = 0;
    for (int ks = 0; ks < 8; ++ks) {
        if (ks < 7) STAGE(cur ^ 1, (ks + 1) * 64);   // issue next tile FIRST
        const unsigned short* AbL = (const unsigned short*)(smem + cur * 16384);
        const unsigned short* WbL = (const unsigned short*)(smem + cur * 16384 + 8192);
        #pragma unroll
        for (int kq = 0; kq < 2; ++kq) {
            const int scol = (kq * 32 + qd * 8) ^ ((lm & 7) * 8);  // swizzled read col
            const short8 af = *(const short8*)&AbL[(w * 16 + lm) * 64 + scol];
            #pragma unroll
            for (int nt = 0; nt < 4; ++nt) {
                const short8 bf = *(const short8*)&WbL[(nt * 16 + lm) * 64 + scol];
                acc[nt] = __builtin_amdgcn_mfma_f32_16x16x32_bf16(af, bf, acc[nt], 0, 0, 0);
            }
        }
        __syncthreads();             // drains next-tile loads + read-protects cur
        cur ^= 1;
    }

    if (op == 0) {
        #pragma unroll
        for (int nt = 0; nt < 4; ++nt) {
            const int c = bj + nt * 16 + lm;
            const float bb = bias[c];
            #pragma unroll
            for (int reg = 0; reg < 4; ++reg) {
                const int r = arow + w * 16 + qd * 4 + reg;
                qout[(size_t)r * 512 + c] = f2bf((acc[nt][reg] + bb) * 0.0625f);
            }
        }
        return;
    }

    const int h = bj >> 8;
    const int bj_rel = bj & 255;

    if (op == 1) {
        #pragma unroll
        for (int nt = 0; nt < 4; ++nt) {
            const int dl = nt * 16 + lm;
            const float bb = bias[bj + dl];
            #pragma unroll
            for (int reg = 0; reg < 4; ++reg)
                Eb[w * 16 + qd * 4 + reg][dl] = f2bf(acc[nt][reg] + bb);
        }
        __syncthreads();
        const size_t base = ((size_t)(h * 128 + a)) * 16384;
        #pragma unroll
        for (int i = 0; i < 2; ++i) {
            const int s = tid + i * 256;
            const int ntf = s >> 7, kqr = (s >> 6) & 1, l = s & 63;
            const int v = ntf * 16 + (l & 15);
            const int dl = kqr * 32 + (l >> 4) * 8;
            ushort8 val = *(const ushort8*)&Eb[v][dl];
            *(ushort8*)&Kgf[base + ((size_t)(ntf * 8 + (bj_rel >> 5) + kqr) * 64 + l) * 8] = val;
        }
    } else {
        #pragma unroll
        for (int nt = 0; nt < 4; ++nt) {
            const int dl = nt * 16 + lm;
            const float bb = bias[bj + dl];
            #pragma unroll
            for (int reg = 0; reg < 4; ++reg)
                Eb[dl][w * 16 + qd * 4 + reg] = f2bf(acc[nt][reg] + bb);
        }
        __syncthreads();
        const size_t base = ((size_t)(h * 128 + a)) * 16384;
        #pragma unroll
        for (int i = 0; i < 2; ++i) {
            const int s = tid + i * 256;
            const int ntr = s >> 7, kqv = (s >> 6) & 1, l = s & 63;
            const int dl = ntr * 16 + (l & 15);
            const int v0 = kqv * 32 + (l >> 4) * 8;
            ushort8 val = *(const ushort8*)&Eb[dl][v0];
            *(ushort8*)&Vgf[base + ((size_t)(((bj_rel >> 4) + ntr) * 2 + kqv) * 64 + l) * 8] = val;
        }
    }
}

// ===========================================================================
// attn9 (exact r1-verified source, setprio REVERTED — T5 is negative on this
// lockstep structure, m190-consistent, measured 56.6 vs 61.8 with setprio).
// Grid (8 chunks, 2 h, 16 tg) = 256 blocks, 512 thr (8 waves), 1/CU.
// Wave w: text wt = w>>1 (full 32 words), role bit fh = w&1:
//   QK: frame-half fh (swapped operands mfma(K,Q) -> D[frame][word])
//   PV: d-half fh
// Split softmax combined across the wave pair via Ex; P via LDS (frag-major).
// K/V double-buffered, global_load_lds staged 2 vids ahead.
// ===========================================================================
__global__ __launch_bounds__(512, 2)
void attn9(const unsigned short* __restrict__ Kgf,
           const unsigned short* __restrict__ Vgf,
           const unsigned short* __restrict__ q,    // bf16, pre-scaled 1/16
           unsigned short* __restrict__ partg) {    // [8][2048][512] bf16
    const int c  = blockIdx.x;
    const int h  = blockIdx.y;
    const int tg = blockIdx.z;
    const int tid = threadIdx.x;
    const int w = tid >> 6, lane = tid & 63;
    const int lm = lane & 15, qd = lane >> 4;
    const int wt = w >> 1;       // text slot 0..3
    const int fh = w & 1;        // frame-half (QK) / d-half (PV)
    const int b = tg * 4 + wt;

    __shared__ __align__(16) unsigned short Kb[2][16384];     // 64 KB
    __shared__ __align__(16) unsigned short Vb[2][16384];     // 64 KB
    __shared__ __align__(16) unsigned short Pf[4][2][2][512]; // [text][mt][kqv][l*8+j] 16 KB
    __shared__ __align__(16) float Ex[4][2][2][16][2];        // [text][fh][mt][word16][m,s] 2 KB

    // Q B-frags for the wave's full text: 16 frags = 64 VGPRs
    short8 qf[2][8];
    #pragma unroll
    for (int mt = 0; mt < 2; ++mt)
        #pragma unroll
        for (int kq = 0; kq < 8; ++kq)
            qf[mt][kq] = *(const short8*)
                &q[((size_t)(b * 32 + mt * 16 + lm)) * 512 + h * 256 + kq * 32 + qd * 8];

    float4v pacc[2][8];
    #pragma unroll
    for (int mt = 0; mt < 2; ++mt)
        #pragma unroll
        for (int nd = 0; nd < 8; ++nd) pacc[mt][nd] = (float4v){0.f, 0.f, 0.f, 0.f};

    const size_t vb0 = (size_t)(h * 128 + c * 16) * 16384;

    // prologue: stage vids 0 and 1 into the two buffers
    #pragma unroll
    for (int i = 0; i < 4; ++i) {
        const int s = tid + i * 512;
        gload_lds16(&Kb[0][(size_t)s * 8], &Kgf[vb0 + (size_t)s * 8]);
        gload_lds16(&Vb[0][(size_t)s * 8], &Vgf[vb0 + (size_t)s * 8]);
    }
    #pragma unroll
    for (int i = 0; i < 4; ++i) {
        const int s = tid + i * 512;
        gload_lds16(&Kb[1][(size_t)s * 8], &Kgf[vb0 + 16384 + (size_t)s * 8]);
        gload_lds16(&Vb[1][(size_t)s * 8], &Vgf[vb0 + 16384 + (size_t)s * 8]);
    }
    __syncthreads();

    for (int ai = 0; ai < 16; ++ai) {
        const int cur = ai & 1;

        // ---- QK: D[frame][word], frames = fh*32 + nt*16 + qd*4 + reg ----
        float4v lacc[2][2];   // [nt frame-tile][mt word-tile]
        #pragma unroll
        for (int nt = 0; nt < 2; ++nt)
            #pragma unroll
            for (int mt = 0; mt < 2; ++mt) lacc[nt][mt] = (float4v){0.f, 0.f, 0.f, 0.f};
        #pragma unroll
        for (int kq = 0; kq < 8; ++kq) {
            #pragma unroll
            for (int nt = 0; nt < 2; ++nt) {
                const short8 kf = *(const short8*)
                    &Kb[cur][(((fh * 2 + nt) * 8 + kq) * 64 + lane) * 8];
                lacc[nt][0] = __builtin_amdgcn_mfma_f32_16x16x32_bf16(kf, qf[0][kq], lacc[nt][0], 0, 0, 0);
                lacc[nt][1] = __builtin_amdgcn_mfma_f32_16x16x32_bf16(kf, qf[1][kq], lacc[nt][1], 0, 0, 0);
            }
        }

        // ---- local softmax over this wave's 32 frames (8 in-lane + 2 shfl) ----
        float m2[2], sv[2], e[2][2][4];
        #pragma unroll
        for (int mt = 0; mt < 2; ++mt) {
            float mm = lacc[0][mt][0];
            #pragma unroll
            for (int nt = 0; nt < 2; ++nt)
                #pragma unroll
                for (int r = 0; r < 4; ++r) mm = fmaxf(mm, lacc[nt][mt][r]);
            mm = fmaxf(mm, __shfl_xor(mm, 16));
            mm = fmaxf(mm, __shfl_xor(mm, 32));
            float ss = 0.f;
            #pragma unroll
            for (int nt = 0; nt < 2; ++nt)
                #pragma unroll
                for (int r = 0; r < 4; ++r) {
                    const float ev = __expf(lacc[nt][mt][r] - mm);
                    e[mt][nt][r] = ev;
                    ss += ev;
                }
            ss += __shfl_xor(ss, 16);
            ss += __shfl_xor(ss, 32);
            m2[mt] = mm; sv[mt] = ss;
            if (qd == 0) {
                Ex[wt][fh][mt][lm][0] = mm;
                Ex[wt][fh][mt][lm][1] = ss;
            }
        }
        __syncthreads();   // B3: (m,s) exchange visible

        // ---- combine halves, scale P, write frag-major P ----
        #pragma unroll
        for (int mt = 0; mt < 2; ++mt) {
            const float om = Ex[wt][fh ^ 1][mt][lm][0];
            const float os = Ex[wt][fh ^ 1][mt][lm][1];
            const float M   = fmaxf(m2[mt], om);
            const float den = sv[mt] * __expf(m2[mt] - M) + os * __expf(om - M);
            const float fac = __expf(m2[mt] - M) / den;
            #pragma unroll
            for (int nt = 0; nt < 2; ++nt) {
                ushort4v pv;
                pv.x = f2bf(e[mt][nt][0] * fac);
                pv.y = f2bf(e[mt][nt][1] * fac);
                pv.z = f2bf(e[mt][nt][2] * fac);
                pv.w = f2bf(e[mt][nt][3] * fac);
                // fl = nt*16 + qd*4 + reg; dest (l', j) = (lm + 16*(fl>>3), fl&7)
                *(ushort4v*)&Pf[wt][mt][fh][(lm + 16 * (nt * 2 + (qd >> 1))) * 8 + (qd & 1) * 4] = pv;
            }
        }
        __syncthreads();   // B4: P visible to the partner wave

        // ---- PV: out[word][d], d = fh*128 + nd*16 + lm ----
        #pragma unroll
        for (int kqv = 0; kqv < 2; ++kqv) {
            const short8 pf0 = *(const short8*)&Pf[wt][0][kqv][lane * 8];
            const short8 pf1 = *(const short8*)&Pf[wt][1][kqv][lane * 8];
            #pragma unroll
            for (int nd = 0; nd < 8; ++nd) {
                const short8 vf = *(const short8*)
                    &Vb[cur][(((fh * 8 + nd) * 2 + kqv) * 64 + lane) * 8];
                pacc[0][nd] = __builtin_amdgcn_mfma_f32_16x16x32_bf16(pf0, vf, pacc[0][nd], 0, 0, 0);
                pacc[1][nd] = __builtin_amdgcn_mfma_f32_16x16x32_bf16(pf1, vf, pacc[1][nd], 0, 0, 0);
            }
        }
        __syncthreads();   // B1: all waves done with Kb/Vb[cur] and Pf

        // stage vid ai+2 into the buffer just freed (2-ahead prefetch)
        if (ai < 14) {
            const size_t kb = vb0 + (size_t)(ai + 2) * 16384;
            #pragma unroll
            for (int i = 0; i < 4; ++i) {
                const int s = tid + i * 512;
                gload_lds16(&Kb[cur][(size_t)s * 8], &Kgf[kb + (size_t)s * 8]);
                gload_lds16(&Vb[cur][(size_t)s * 8], &Vgf[kb + (size_t)s * 8]);
            }
        }
    }

    // epilogue: row = b*32 + h*16 + (t>>1), col = (t&1)*256 + d (verified remap)
    unsigned short* part = partg + (size_t)c * 1048576;
    #pragma unroll
    for (int mt = 0; mt < 2; ++mt)
        #pragma unroll
        for (int nd = 0; nd < 8; ++nd)
            #pragma unroll
            for (int r = 0; r < 4; ++r) {
                const int t = mt * 16 + qd * 4 + r;
                const int d = fh * 128 + nd * 16 + lm;
                const int row = b * 32 + h * 16 + (t >> 1);
                const int col = (t & 1) * 256 + d;
                part[(size_t)row * 512 + col] = f2bf(pacc[mt][nd][r]);
            }
}

// ===========================================================================
// reduce8: partg[0][i] = (sum_p partg[p][i]) / 128, bf16 (single rounding).
// ===========================================================================
__global__ __launch_bounds__(256)
void reduce8(unsigned short* __restrict__ partg) {
    const size_t i = ((size_t)blockIdx.x * 256 + threadIdx.x) * 8;
    float s[8];
    #pragma unroll
    for (int j = 0; j < 8; ++j) s[j] = 0.f;
    #pragma unroll
    for (int p = 0; p < 8; ++p) {
        ushort8 u = *(const ushort8*)&partg[(size_t)p * 1048576 + i];
        #pragma unroll
        for (int j = 0; j < 8; ++j) s[j] += bf2f(u[j]);
    }
    ushort8 o;
    #pragma unroll
    for (int j = 0; j < 8; ++j) o[j] = f2bf(s[j] * 0.0078125f);
    *(ushort8*)&partg[i] = o;
}

// ===========================================================================
// proj_o: out = Abf @ Wo^T + bo, fp32 out. (unchanged, verified)
// ===========================================================================
__global__ __launch_bounds__(256)
void proj_o(const unsigned short* __restrict__ Abf, const float* __restrict__ W,
            const float* __restrict__ bias, float* __restrict__ C) {
    __shared__ __align__(16) unsigned short Ab[64][72];
    __shared__ __align__(16) unsigned short Wb[64][72];
    const int tid = threadIdx.x;
    const int bi = blockIdx.x * 64, bj = blockIdx.y * 64;
    const int w = tid >> 6, lane = tid & 63;
    const int lm = lane & 15, qd = lane >> 4;

    float4v acc[4];
    #pragma unroll
    for (int nt = 0; nt < 4; ++nt) acc[nt] = (float4v){0.f, 0.f, 0.f, 0.f};

    for (int k0 = 0; k0 < 512; k0 += 64) {
        #pragma unroll
        for (int it = 0; it < 2; ++it) {
            const int s = tid + it * 256;
            const int r = s >> 3, c8 = (s & 7) * 8;
            *(ushort8*)&Ab[r][c8] = *(const ushort8*)&Abf[(size_t)(bi + r) * 512 + k0 + c8];
        }
        #pragma unroll
        for (int it = 0; it < 4; ++it) {
            const int s = tid + it * 256;
            const int r = s >> 4, c4 = (s & 15) * 4;
            float4v fw = *(const float4v*)&W[(size_t)(bj + r) * 512 + k0 + c4];
            *(ushort4v*)&Wb[r][c4] = (ushort4v){f2bf(fw.x), f2bf(fw.y), f2bf(fw.z), f2bf(fw.w)};
        }
        __syncthreads();
        #pragma unroll
        for (int kq = 0; kq < 2; ++kq) {
            const short8 af = *(const short8*)&Ab[w * 16 + lm][kq * 32 + qd * 8];
            #pragma unroll
            for (int nt = 0; nt < 4; ++nt) {
                const short8 bf = *(const short8*)&Wb[nt * 16 + lm][kq * 32 + qd * 8];
                acc[nt] = __builtin_amdgcn_mfma_f32_16x16x32_bf16(af, bf, acc[nt], 0, 0, 0);
            }
        }
        __syncthreads();
    }
    #pragma unroll
    for (int nt = 0; nt < 4; ++nt) {
        const int cc = bj + nt * 16 + lm;
        const float bb = bias[cc];
        #pragma unroll
        for (int reg = 0; reg < 4; ++reg) {
            const int r = bi + w * 16 + qd * 4 + reg;
            C[(size_t)r * 512 + cc] = acc[nt][reg] + bb;
        }
    }
}

extern "C" void kernel_launch(void* const* d_in, const int* in_sizes, int n_in,
                              void* d_out, int out_size, void* d_ws, size_t ws_size,
                              hipStream_t stream) {
    const float* text  = (const float*)d_in[0];
    const float* video = (const float*)d_in[1];
    const float* Wq = (const float*)d_in[2];
    const float* bq = (const float*)d_in[3];
    const float* Wk = (const float*)d_in[4];
    const float* bk = (const float*)d_in[5];
    const float* Wv = (const float*)d_in[6];
    const float* bv = (const float*)d_in[7];
    const float* Wo = (const float*)d_in[8];
    const float* bo = (const float*)d_in[9];

    // ws (32 MB): Kgf 8 MB @0; Vgf 8 MB @8MB; partg bf16 [8][2048][512] @16MB.
    // The partg region doubles as the bf16-input scratch (11.5 MB) for cvt5 +
    // proj_qkv — it is only overwritten by attn9, which runs after proj_qkv.
    // q bf16 [2048][512] (pre-scaled 1/16) lives in d_out [0,2MB) until proj_o.
    unsigned short* Kgf   = (unsigned short*)d_ws;
    unsigned short* Vgf   = (unsigned short*)((char*)d_ws + (8u << 20));
    unsigned short* partg = (unsigned short*)((char*)d_ws + (16u << 20));
    unsigned short* textbf  = partg;
    unsigned short* videobf = partg + 1048576;
    unsigned short* wqbf    = partg + 5242880;
    unsigned short* wkbf    = partg + 5505024;
    unsigned short* wvbf    = partg + 5767168;
    unsigned short* qbf   = (unsigned short*)d_out;
    float*          out   = (float*)d_out;

    cvt5<<<dim3(512, 5), 256, 0, stream>>>(text, video, Wq, Wk, Wv, partg);
    proj_qkv<<<dim3(288, 8), 256, 0, stream>>>(textbf, videobf, wqbf, bq, wkbf, bk,
                                               wvbf, bv, qbf, Kgf, Vgf);
    attn9<<<dim3(8, 2, 16), 512, 0, stream>>>(Kgf, Vgf, qbf, partg);
    reduce8<<<dim3(512), 256, 0, stream>>>(partg);
    proj_o<<<dim3(32, 8), 256, 0, stream>>>(partg, Wo, bo, out);
}